// Round 5
// baseline (305.304 us; speedup 1.0000x reference)
//
#include <hip/hip_runtime.h>
#include <math.h>

#define NN 50000
#define NE 500000
#define HH 4
#define CC 64
#define HC 256
#define PD 16
#define XD 272
#define NEG 0.2f
#define SB 1024
#define NBLK (NN / 4)   // k_node blocks

typedef _Float16 half4 __attribute__((ext_vector_type(4)));
typedef _Float16 half8 __attribute__((ext_vector_type(8)));
typedef float floatx4 __attribute__((ext_vector_type(4)));

// ---------------- prep: zero counts/cursor + swizzle W into fp16 MFMA-fragment order ----------------
// wfrag[(((kt*4+wv)*4+nt)*64 + lane)*8 + j] = W[wv*64+nt*16+(lane&15)][kt*32+(lane>>4)*8+j]
__global__ void k_prep(const float* __restrict__ w, _Float16* __restrict__ wfrag,
                       int* __restrict__ counts, int* __restrict__ gcur) {
    int idx = blockIdx.x * blockDim.x + threadIdx.x;   // 65536 threads
    if (idx < NN) counts[idx] = 0;
    if (idx == NN) *gcur = 0;
    int j = idx & 7, lane = (idx >> 3) & 63, nt = (idx >> 9) & 3;
    int wv = (idx >> 11) & 3, kt = idx >> 13;
    int n = wv * 64 + nt * 16 + (lane & 15);
    int k = kt * 32 + (lane >> 4) * 8 + j;
    wfrag[idx] = (_Float16)w[(size_t)n * 256 + k];
}

// ---------------- MFMA GEMM: content(fp16) = Xc @ W^T, fused attention scores ----------------
// block = 256 thr (4 waves). Tile: 64 nodes x 256 cols; wave wv = head wv.
// NO LDS, NO barriers: A-frags direct from x (fp32->fp16 in-reg), B-frags from wfrag (L2-hot).
__global__ __launch_bounds__(256) void k_gemm(const float* __restrict__ x,
                                              const _Float16* __restrict__ wfrag,
                                              const float* __restrict__ att,
                                              const float* __restrict__ patt,
                                              _Float16* __restrict__ content,
                                              float* __restrict__ ssrc,
                                              float* __restrict__ sdst) {
    const int tid = threadIdx.x;
    const int wv = tid >> 6, lane = tid & 63;
    const int nb = blockIdx.x * 64;
    const int m16 = lane & 15, q = lane >> 4;

    floatx4 acc[4][4];
#pragma unroll
    for (int mt = 0; mt < 4; mt++)
#pragma unroll
        for (int nt = 0; nt < 4; nt++) acc[mt][nt] = (floatx4){0.f, 0.f, 0.f, 0.f};

    // A row base pointers (clamped; stores are guarded)
    const float* xr[4];
#pragma unroll
    for (int mt = 0; mt < 4; mt++) {
        int node = nb + mt * 16 + m16;
        if (node >= NN) node = NN - 1;
        xr[mt] = &x[(size_t)node * XD + q * 8];
    }

#pragma unroll
    for (int kt = 0; kt < 8; kt++) {
        half8 bf[4];
#pragma unroll
        for (int nt = 0; nt < 4; nt++)
            bf[nt] = *(const half8*)&wfrag[((((size_t)kt * 4 + wv) * 4 + nt) * 64 + lane) * 8];
        half8 af[4];
#pragma unroll
        for (int mt = 0; mt < 4; mt++) {
            float4 f0 = *(const float4*)(xr[mt] + kt * 32);
            float4 f1 = *(const float4*)(xr[mt] + kt * 32 + 4);
            half8 hv;
            hv[0] = (_Float16)f0.x; hv[1] = (_Float16)f0.y;
            hv[2] = (_Float16)f0.z; hv[3] = (_Float16)f0.w;
            hv[4] = (_Float16)f1.x; hv[5] = (_Float16)f1.y;
            hv[6] = (_Float16)f1.z; hv[7] = (_Float16)f1.w;
            af[mt] = hv;
        }
#pragma unroll
        for (int mt = 0; mt < 4; mt++)
#pragma unroll
            for (int nt = 0; nt < 4; nt++)
                acc[mt][nt] = __builtin_amdgcn_mfma_f32_16x16x32_f16(
                    af[mt], bf[nt], acc[mt][nt], 0, 0, 0);
    }

    // epilogue: D layout col(in head) = nt*16 + (lane&15), node = nb + mt*16 + q*4 + r
    const int h = wv;
#pragma unroll
    for (int mt = 0; mt < 4; mt++) {
#pragma unroll
        for (int r = 0; r < 4; r++) {
            int node = nb + mt * 16 + q * 4 + r;
            if (node < NN) {
                float sa = 0.f, sb = 0.f;
#pragma unroll
                for (int nt = 0; nt < 4; nt++) {
                    float v = acc[mt][nt][r];
                    int cih = nt * 16 + m16;
                    content[(size_t)node * 256 + h * 64 + cih] = (_Float16)v;
                    sa += v * att[h * 128 + cih];
                    sb += v * att[h * 128 + 64 + cih];
                }
                float pv = x[(size_t)node * XD + 256 + m16];
                sa += pv * patt[h * 32 + m16];
                sb += pv * patt[h * 32 + 16 + m16];
#pragma unroll
                for (int m = 1; m < 16; m <<= 1) {
                    sa += __shfl_xor(sa, m, 64);
                    sb += __shfl_xor(sb, m, 64);
                }
                if (m16 == 0) {
                    ssrc[node * 4 + h] = sa;
                    sdst[node * 4 + h] = sb;
                }
            }
        }
    }
}

// ---------------- edge bucketing by row (count returns slot; place is atomic-free) ----------------
__global__ void k_count(const int* __restrict__ row, int* __restrict__ counts,
                        int* __restrict__ slot) {
    int e = blockIdx.x * blockDim.x + threadIdx.x;
    if (e < NE) slot[e] = atomicAdd(&counts[row[e]], 1);
}

// ---------------- offsets: per-block scan + atomic base (node order irrelevant) ----------------
__global__ __launch_bounds__(SB) void k_offs(const int* __restrict__ counts,
                                             int* __restrict__ offs,
                                             int* __restrict__ gcur) {
    __shared__ int s[SB];
    __shared__ int basesh;
    int i = blockIdx.x * SB + threadIdx.x;
    int v = (i < NN) ? counts[i] : 0;
    s[threadIdx.x] = v;
    __syncthreads();
    for (int off = 1; off < SB; off <<= 1) {
        int t = (threadIdx.x >= off) ? s[threadIdx.x - off] : 0;
        __syncthreads();
        s[threadIdx.x] += t;
        __syncthreads();
    }
    if (threadIdx.x == SB - 1) basesh = atomicAdd(gcur, s[SB - 1]);
    __syncthreads();
    if (i < NN) offs[i] = basesh + s[threadIdx.x] - v;   // exclusive within block
}

__global__ void k_place(const int* __restrict__ row, const int* __restrict__ col,
                        const int* __restrict__ offs, const int* __restrict__ slot,
                        int* __restrict__ sorted) {
    int e = blockIdx.x * blockDim.x + threadIdx.x;
    if (e < NE) sorted[offs[row[e]] + slot[e]] = col[e];
}

// ---------------- per-node softmax + aggregation (1 wave / node) ----------------
__global__ __launch_bounds__(256) void k_node(const _Float16* __restrict__ content,
                                              const float* __restrict__ ssrc,
                                              const float* __restrict__ sdst,
                                              const int* __restrict__ counts,
                                              const int* __restrict__ off,
                                              const int* __restrict__ sorted,
                                              const float* __restrict__ bias,
                                              float* __restrict__ out,
                                              float* __restrict__ gpart) {
    __shared__ float gsh[16];
    __shared__ float ash[4][64][4];   // per-wave alpha cache [wave][edge][head]
    __shared__ int   csh[4][64];      // per-wave col cache
    const int w = threadIdx.x >> 6;
    const int lane = threadIdx.x & 63;
    const int n = blockIdx.x * 4 + w;   // NN % 4 == 0
    if (threadIdx.x < 16) gsh[threadIdx.x] = 0.f;
    __syncthreads();

    const int cnt = counts[n], base = off[n];
    const int total = cnt + 1;  // + self loop
    const float4 ss = *(const float4*)&ssrc[n * 4];
    const int hsel = lane >> 4;
    const half4* c4 = (const half4*)content;

    float4 acc = make_float4(0.f, 0.f, 0.f, 0.f);
    float g[10];
#pragma unroll
    for (int k = 0; k < 10; k++) g[k] = 0.f;

    if (total <= 64) {
        // ---- fast path: one edge per lane ----
        const int l = lane;
        const bool act = (l < total);
        const int c = (l < cnt) ? sorted[base + l] : n;
        float4 sd = *(const float4*)&sdst[c * 4];
        float r0 = ss.x + sd.x; r0 = r0 > 0.f ? r0 : NEG * r0;
        float r1 = ss.y + sd.y; r1 = r1 > 0.f ? r1 : NEG * r1;
        float r2 = ss.z + sd.z; r2 = r2 > 0.f ? r2 : NEG * r2;
        float r3 = ss.w + sd.w; r3 = r3 > 0.f ? r3 : NEG * r3;
        float m0 = act ? r0 : -1e30f, m1 = act ? r1 : -1e30f;
        float m2 = act ? r2 : -1e30f, m3 = act ? r3 : -1e30f;
#pragma unroll
        for (int s = 1; s < 64; s <<= 1) {
            m0 = fmaxf(m0, __shfl_xor(m0, s));
            m1 = fmaxf(m1, __shfl_xor(m1, s));
            m2 = fmaxf(m2, __shfl_xor(m2, s));
            m3 = fmaxf(m3, __shfl_xor(m3, s));
        }
        float e0 = act ? __expf(r0 - m0) : 0.f;
        float e1 = act ? __expf(r1 - m1) : 0.f;
        float e2 = act ? __expf(r2 - m2) : 0.f;
        float e3 = act ? __expf(r3 - m3) : 0.f;
        float s0 = e0, s1 = e1, s2 = e2, s3 = e3;
#pragma unroll
        for (int s = 1; s < 64; s <<= 1) {
            s0 += __shfl_xor(s0, s); s1 += __shfl_xor(s1, s);
            s2 += __shfl_xor(s2, s); s3 += __shfl_xor(s3, s);
        }
        float a0 = e0 / (s0 + 1e-16f), a1 = e1 / (s1 + 1e-16f);
        float a2 = e2 / (s2 + 1e-16f), a3 = e3 / (s3 + 1e-16f);

        g[0] = a0 * a0; g[1] = a0 * a1; g[2] = a0 * a2; g[3] = a0 * a3;
        g[4] = a1 * a1; g[5] = a1 * a2; g[6] = a1 * a3;
        g[7] = a2 * a2; g[8] = a2 * a3; g[9] = a3 * a3;

        // inactive lanes: alpha = 0, col = n -> safe padding
        ash[w][l][0] = a0; ash[w][l][1] = a1;
        ash[w][l][2] = a2; ash[w][l][3] = a3;
        csh[w][l] = c;

        // ---- aggregation: branch-free 8-wide, 8 gathers in flight ----
        // (16-wide measured WORSE: VGPR 40->64, occupancy 58->40, +16 us. Keep 8.)
        const int nit = (total + 7) & ~7;
        for (int e = 0; e < nit; e += 8) {
            int   ci[8];
            float bi[8];
#pragma unroll
            for (int u = 0; u < 8; u++) {
                ci[u] = csh[w][e + u];
                bi[u] = ash[w][e + u][hsel];
            }
            half4 vi[8];
#pragma unroll
            for (int u = 0; u < 8; u++) vi[u] = c4[(size_t)ci[u] * 64 + lane];
#pragma unroll
            for (int u = 0; u < 8; u++) {
                acc.x += bi[u] * (float)vi[u][0];
                acc.y += bi[u] * (float)vi[u][1];
                acc.z += bi[u] * (float)vi[u][2];
                acc.w += bi[u] * (float)vi[u][3];
            }
        }
    } else {
        // ---- generic chunked path (degree >= 64; essentially never) ----
        const int nch = (total + 63) >> 6;
        float m0 = -1e30f, m1 = -1e30f, m2 = -1e30f, m3 = -1e30f;
        for (int ch = 0; ch < nch; ch++) {
            int l = ch * 64 + lane;
            if (l < total) {
                int c = (l < cnt) ? sorted[base + l] : n;
                float4 sd = *(const float4*)&sdst[c * 4];
                float r0 = ss.x + sd.x; r0 = r0 > 0.f ? r0 : NEG * r0;
                float r1 = ss.y + sd.y; r1 = r1 > 0.f ? r1 : NEG * r1;
                float r2 = ss.z + sd.z; r2 = r2 > 0.f ? r2 : NEG * r2;
                float r3 = ss.w + sd.w; r3 = r3 > 0.f ? r3 : NEG * r3;
                m0 = fmaxf(m0, r0); m1 = fmaxf(m1, r1);
                m2 = fmaxf(m2, r2); m3 = fmaxf(m3, r3);
            }
        }
#pragma unroll
        for (int s = 1; s < 64; s <<= 1) {
            m0 = fmaxf(m0, __shfl_xor(m0, s));
            m1 = fmaxf(m1, __shfl_xor(m1, s));
            m2 = fmaxf(m2, __shfl_xor(m2, s));
            m3 = fmaxf(m3, __shfl_xor(m3, s));
        }
        float s0 = 0.f, s1 = 0.f, s2 = 0.f, s3 = 0.f;
        for (int ch = 0; ch < nch; ch++) {
            int l = ch * 64 + lane;
            if (l < total) {
                int c = (l < cnt) ? sorted[base + l] : n;
                float4 sd = *(const float4*)&sdst[c * 4];
                float r0 = ss.x + sd.x; r0 = r0 > 0.f ? r0 : NEG * r0;
                float r1 = ss.y + sd.y; r1 = r1 > 0.f ? r1 : NEG * r1;
                float r2 = ss.z + sd.z; r2 = r2 > 0.f ? r2 : NEG * r2;
                float r3 = ss.w + sd.w; r3 = r3 > 0.f ? r3 : NEG * r3;
                s0 += __expf(r0 - m0); s1 += __expf(r1 - m1);
                s2 += __expf(r2 - m2); s3 += __expf(r3 - m3);
            }
        }
#pragma unroll
        for (int s = 1; s < 64; s <<= 1) {
            s0 += __shfl_xor(s0, s); s1 += __shfl_xor(s1, s);
            s2 += __shfl_xor(s2, s); s3 += __shfl_xor(s3, s);
        }
        const float i0 = 1.f / (s0 + 1e-16f), i1 = 1.f / (s1 + 1e-16f);
        const float i2 = 1.f / (s2 + 1e-16f), i3 = 1.f / (s3 + 1e-16f);

        for (int ch = 0; ch < nch; ch++) {
            int l = ch * 64 + lane;
            int c = n;
            float a0 = 0.f, a1 = 0.f, a2 = 0.f, a3 = 0.f;
            if (l < total) {
                c = (l < cnt) ? sorted[base + l] : n;
                float4 sd = *(const float4*)&sdst[c * 4];
                float r0 = ss.x + sd.x; r0 = r0 > 0.f ? r0 : NEG * r0;
                float r1 = ss.y + sd.y; r1 = r1 > 0.f ? r1 : NEG * r1;
                float r2 = ss.z + sd.z; r2 = r2 > 0.f ? r2 : NEG * r2;
                float r3 = ss.w + sd.w; r3 = r3 > 0.f ? r3 : NEG * r3;
                a0 = __expf(r0 - m0) * i0; a1 = __expf(r1 - m1) * i1;
                a2 = __expf(r2 - m2) * i2; a3 = __expf(r3 - m3) * i3;
            }
            g[0] += a0 * a0; g[1] += a0 * a1; g[2] += a0 * a2; g[3] += a0 * a3;
            g[4] += a1 * a1; g[5] += a1 * a2; g[6] += a1 * a3;
            g[7] += a2 * a2; g[8] += a2 * a3; g[9] += a3 * a3;

            int cc = min(64, total - ch * 64);
            for (int e = 0; e < cc; e++) {
                float b0 = __shfl(a0, e), b1 = __shfl(a1, e);
                float b2 = __shfl(a2, e), b3 = __shfl(a3, e);
                int ce = __shfl(c, e);
                float mya = hsel == 0 ? b0 : hsel == 1 ? b1 : hsel == 2 ? b2 : b3;
                half4 cv = c4[(size_t)ce * 64 + lane];
                acc.x += mya * (float)cv[0]; acc.y += mya * (float)cv[1];
                acc.z += mya * (float)cv[2]; acc.w += mya * (float)cv[3];
            }
        }
    }

    float4 bv = ((const float4*)bias)[lane];
    acc.x += bv.x; acc.y += bv.y; acc.z += bv.z; acc.w += bv.w;
    ((float4*)out)[(size_t)n * 64 + lane] = acc;

    // gram: wave reduce -> LDS -> per-block partial STORE (no global atomics)
#pragma unroll
    for (int s = 1; s < 64; s <<= 1) {
#pragma unroll
        for (int k = 0; k < 10; k++) g[k] += __shfl_xor(g[k], s);
    }
    if (lane == 0) {
#pragma unroll
        for (int k = 0; k < 10; k++) atomicAdd(&gsh[k], g[k]);
    }
    __syncthreads();
    if (threadIdx.x < 10) gpart[(size_t)blockIdx.x * 10 + threadIdx.x] = gsh[threadIdx.x];
}

// ---------------- gram reduction + diversity loss ----------------
__global__ __launch_bounds__(1024) void k_final(const float* __restrict__ gpart,
                                                float* __restrict__ out_div) {
    __shared__ float s[1024];
    const int t = threadIdx.x;
    const int k = t & 15, grp = t >> 4;   // 64 groups x 16 slots
    float v = 0.f;
    if (k < 10) {
        for (int b = grp; b < NBLK; b += 64) v += gpart[(size_t)b * 10 + k];
    }
    s[t] = v;
    __syncthreads();
    for (int off = 512; off >= 16; off >>= 1) {
        if (t < off) s[t] += s[t + off];
        __syncthreads();
    }
    if (t == 0) {
        float g00 = s[0], g01 = s[1], g02 = s[2], g03 = s[3];
        float g11 = s[4], g12 = s[5], g13 = s[6];
        float g22 = s[7], g23 = s[8], g33 = s[9];
        float n0 = fmaxf(sqrtf(g00), 1e-8f), n1 = fmaxf(sqrtf(g11), 1e-8f);
        float n2 = fmaxf(sqrtf(g22), 1e-8f), n3 = fmaxf(sqrtf(g33), 1e-8f);
        float sum = g01 / (n0 * n1) + g02 / (n0 * n2) + g03 / (n0 * n3) +
                    g12 / (n1 * n2) + g13 / (n1 * n3) + g23 / (n2 * n3);
        sum *= 2.0f;
        out_div[0] = sum / 16.0f * 0.1f;
    }
}

extern "C" void kernel_launch(void* const* d_in, const int* in_sizes, int n_in,
                              void* d_out, int out_size, void* d_ws, size_t ws_size,
                              hipStream_t stream) {
    const float* x    = (const float*)d_in[0];
    const int*   ei   = (const int*)d_in[1];
    const int*   row  = ei;
    const int*   col  = ei + NE;
    const float* w    = (const float*)d_in[2];
    const float* att  = (const float*)d_in[3];
    const float* patt = (const float*)d_in[4];
    const float* bias = (const float*)d_in[5];
    float* out = (float*)d_out;

    char* p = (char*)d_ws;
    _Float16* content = (_Float16*)p; p += (size_t)NN * 256 * 2;
    _Float16* wfrag   = (_Float16*)p; p += (size_t)256 * 256 * 2;
    float* ssrc    = (float*)p; p += (size_t)NN * 4 * 4;
    float* sdst    = (float*)p; p += (size_t)NN * 4 * 4;
    float* gpart   = (float*)p; p += (size_t)NBLK * 10 * 4;
    int* counts    = (int*)p;   p += (size_t)NN * 4;
    int* offs      = (int*)p;   p += (size_t)NN * 4;
    int* gcur      = (int*)p;   p += 64;
    int* slot      = (int*)p;   p += (size_t)NE * 4;
    int* sorted    = (int*)p;   p += (size_t)NE * 4;

    k_prep<<<256, 256, 0, stream>>>(w, wfrag, counts, gcur);

    k_count<<<(NE + 255) / 256, 256, 0, stream>>>(row, counts, slot);

    k_gemm<<<(NN + 63) / 64, 256, 0, stream>>>(x, wfrag, att, patt, content, ssrc, sdst);

    int nb1 = (NN + SB - 1) / SB;
    k_offs<<<nb1, SB, 0, stream>>>(counts, offs, gcur);
    k_place<<<(NE + 255) / 256, 256, 0, stream>>>(row, col, offs, slot, sorted);

    k_node<<<NBLK, 256, 0, stream>>>(content, ssrc, sdst, counts, offs, sorted,
                                     bias, out, gpart);
    k_final<<<1, 1024, 0, stream>>>(gpart, out + (size_t)NN * 256);
}

// Round 6
// 289.629 us; speedup vs baseline: 1.0541x; 1.0541x over previous
//
#include <hip/hip_runtime.h>
#include <math.h>

#define NN 50000
#define NE 500000
#define HH 4
#define CC 64
#define HC 256
#define PD 16
#define XD 272
#define NEG 0.2f
#define SB 1024
#define NBLK (NN / 4)   // k_node blocks

typedef _Float16 half4 __attribute__((ext_vector_type(4)));
typedef _Float16 half8 __attribute__((ext_vector_type(8)));
typedef float floatx4 __attribute__((ext_vector_type(4)));

#define ASTR 272   // LDS A row stride in halves

// ---------------- prep: zero counts/cursor + swizzle W into fp16 MFMA-fragment order ----------------
// wfrag[(((kt*4+wv)*4+nt)*64 + lane)*8 + j] = W[wv*64+nt*16+(lane&15)][kt*32+(lane>>4)*8+j]
__global__ void k_prep(const float* __restrict__ w, _Float16* __restrict__ wfrag,
                       int* __restrict__ counts, int* __restrict__ gcur) {
    int idx = blockIdx.x * blockDim.x + threadIdx.x;   // 65536 threads
    if (idx < NN) counts[idx] = 0;
    if (idx == NN) *gcur = 0;
    int j = idx & 7, lane = (idx >> 3) & 63, nt = (idx >> 9) & 3;
    int wv = (idx >> 11) & 3, kt = idx >> 13;
    int n = wv * 64 + nt * 16 + (lane & 15);
    int k = kt * 32 + (lane >> 4) * 8 + j;
    wfrag[idx] = (_Float16)w[(size_t)n * 256 + k];
}

// ---------------- MFMA GEMM: content(fp16) = Xc @ W^T, fused attention scores ----------------
// block = 256 thr (4 waves). Tile: 64 nodes x 256 cols; wave wv = head wv.
// A staged ONCE to LDS (fp16, 64x256, stride 272), single barrier; B from wfrag (L2-hot).
__global__ __launch_bounds__(256) void k_gemm(const float* __restrict__ x,
                                              const _Float16* __restrict__ wfrag,
                                              const float* __restrict__ att,
                                              const float* __restrict__ patt,
                                              _Float16* __restrict__ content,
                                              float* __restrict__ ssrc,
                                              float* __restrict__ sdst) {
    __shared__ _Float16 As[64 * ASTR];
    const int tid = threadIdx.x;
    const int wv = tid >> 6, lane = tid & 63;
    const int nb = blockIdx.x * 64;
    const int m16 = lane & 15, q = lane >> 4;

    // ---- stage A: thread t -> row t>>2, k-base (t&3)*64 (64 floats -> fp16) ----
    {
        const int row = tid >> 2, kb = (tid & 3) * 64;
        int node = nb + row; if (node >= NN) node = NN - 1;   // clamp; stores guarded later
        const float* xp = &x[(size_t)node * XD + kb];
        _Float16* ap = &As[row * ASTR + kb];
#pragma unroll
        for (int i = 0; i < 8; i++) {
            float4 f0 = *(const float4*)(xp + i * 8);
            float4 f1 = *(const float4*)(xp + i * 8 + 4);
            half8 hv;
            hv[0] = (_Float16)f0.x; hv[1] = (_Float16)f0.y;
            hv[2] = (_Float16)f0.z; hv[3] = (_Float16)f0.w;
            hv[4] = (_Float16)f1.x; hv[5] = (_Float16)f1.y;
            hv[6] = (_Float16)f1.z; hv[7] = (_Float16)f1.w;
            *(half8*)(ap + i * 8) = hv;
        }
    }
    __syncthreads();

    floatx4 acc[4][4];
#pragma unroll
    for (int mt = 0; mt < 4; mt++)
#pragma unroll
        for (int nt = 0; nt < 4; nt++) acc[mt][nt] = (floatx4){0.f, 0.f, 0.f, 0.f};

#pragma unroll
    for (int kt = 0; kt < 8; kt++) {
        half8 bf[4];
#pragma unroll
        for (int nt = 0; nt < 4; nt++)
            bf[nt] = *(const half8*)&wfrag[((((size_t)kt * 4 + wv) * 4 + nt) * 64 + lane) * 8];
        half8 af[4];
#pragma unroll
        for (int mt = 0; mt < 4; mt++)
            af[mt] = *(half8*)&As[(mt * 16 + m16) * ASTR + kt * 32 + q * 8];
#pragma unroll
        for (int mt = 0; mt < 4; mt++)
#pragma unroll
            for (int nt = 0; nt < 4; nt++)
                acc[mt][nt] = __builtin_amdgcn_mfma_f32_16x16x32_f16(
                    af[mt], bf[nt], acc[mt][nt], 0, 0, 0);
    }

    // epilogue: D layout col(in head) = nt*16 + (lane&15), node = nb + mt*16 + q*4 + r
    const int h = wv;
#pragma unroll
    for (int mt = 0; mt < 4; mt++) {
#pragma unroll
        for (int r = 0; r < 4; r++) {
            int node = nb + mt * 16 + q * 4 + r;
            if (node < NN) {
                float sa = 0.f, sb = 0.f;
#pragma unroll
                for (int nt = 0; nt < 4; nt++) {
                    float v = acc[mt][nt][r];
                    int cih = nt * 16 + m16;
                    content[(size_t)node * 256 + h * 64 + cih] = (_Float16)v;
                    sa += v * att[h * 128 + cih];
                    sb += v * att[h * 128 + 64 + cih];
                }
                float pv = x[(size_t)node * XD + 256 + m16];
                sa += pv * patt[h * 32 + m16];
                sb += pv * patt[h * 32 + 16 + m16];
#pragma unroll
                for (int m = 1; m < 16; m <<= 1) {
                    sa += __shfl_xor(sa, m, 64);
                    sb += __shfl_xor(sb, m, 64);
                }
                if (m16 == 0) {
                    ssrc[node * 4 + h] = sa;
                    sdst[node * 4 + h] = sb;
                }
            }
        }
    }
}

// ---------------- edge bucketing by row (count returns slot; place is atomic-free) ----------------
__global__ void k_count(const int* __restrict__ row, int* __restrict__ counts,
                        int* __restrict__ slot) {
    int e = blockIdx.x * blockDim.x + threadIdx.x;
    if (e < NE) slot[e] = atomicAdd(&counts[row[e]], 1);
}

// ---------------- offsets: per-block scan + atomic base (node order irrelevant) ----------------
__global__ __launch_bounds__(SB) void k_offs(const int* __restrict__ counts,
                                             int* __restrict__ offs,
                                             int* __restrict__ gcur) {
    __shared__ int s[SB];
    __shared__ int basesh;
    int i = blockIdx.x * SB + threadIdx.x;
    int v = (i < NN) ? counts[i] : 0;
    s[threadIdx.x] = v;
    __syncthreads();
    for (int off = 1; off < SB; off <<= 1) {
        int t = (threadIdx.x >= off) ? s[threadIdx.x - off] : 0;
        __syncthreads();
        s[threadIdx.x] += t;
        __syncthreads();
    }
    if (threadIdx.x == SB - 1) basesh = atomicAdd(gcur, s[SB - 1]);
    __syncthreads();
    if (i < NN) offs[i] = basesh + s[threadIdx.x] - v;   // exclusive within block
}

__global__ void k_place(const int* __restrict__ row, const int* __restrict__ col,
                        const int* __restrict__ offs, const int* __restrict__ slot,
                        int* __restrict__ sorted) {
    int e = blockIdx.x * blockDim.x + threadIdx.x;
    if (e < NE) sorted[offs[row[e]] + slot[e]] = col[e];
}

// ---------------- per-node softmax + aggregation (1 wave / node) ----------------
__global__ __launch_bounds__(256) void k_node(const _Float16* __restrict__ content,
                                              const float* __restrict__ ssrc,
                                              const float* __restrict__ sdst,
                                              const int* __restrict__ counts,
                                              const int* __restrict__ off,
                                              const int* __restrict__ sorted,
                                              const float* __restrict__ bias,
                                              float* __restrict__ out,
                                              float* __restrict__ gpart) {
    __shared__ float gsh[16];
    __shared__ float ashT[4][4][64];  // [wave][head][edge] -> float4 reads in agg loop
    __shared__ int   csh[4][64];      // per-wave col cache
    const int w = threadIdx.x >> 6;
    const int lane = threadIdx.x & 63;
    const int n = blockIdx.x * 4 + w;   // NN % 4 == 0
    if (threadIdx.x < 16) gsh[threadIdx.x] = 0.f;
    __syncthreads();

    const int cnt = counts[n], base = off[n];
    const int total = cnt + 1;  // + self loop
    const float4 ss = *(const float4*)&ssrc[n * 4];
    const int hsel = lane >> 4;
    const half4* c4 = (const half4*)content;

    float4 acc = make_float4(0.f, 0.f, 0.f, 0.f);
    float g[10];
#pragma unroll
    for (int k = 0; k < 10; k++) g[k] = 0.f;

    if (total <= 64) {
        // ---- fast path: one edge per lane ----
        const int l = lane;
        const bool act = (l < total);
        const int c = (l < cnt) ? sorted[base + l] : n;
        float4 sd = *(const float4*)&sdst[c * 4];
        float r0 = ss.x + sd.x; r0 = r0 > 0.f ? r0 : NEG * r0;
        float r1 = ss.y + sd.y; r1 = r1 > 0.f ? r1 : NEG * r1;
        float r2 = ss.z + sd.z; r2 = r2 > 0.f ? r2 : NEG * r2;
        float r3 = ss.w + sd.w; r3 = r3 > 0.f ? r3 : NEG * r3;
        float m0 = act ? r0 : -1e30f, m1 = act ? r1 : -1e30f;
        float m2 = act ? r2 : -1e30f, m3 = act ? r3 : -1e30f;
#pragma unroll
        for (int s = 1; s < 64; s <<= 1) {
            m0 = fmaxf(m0, __shfl_xor(m0, s));
            m1 = fmaxf(m1, __shfl_xor(m1, s));
            m2 = fmaxf(m2, __shfl_xor(m2, s));
            m3 = fmaxf(m3, __shfl_xor(m3, s));
        }
        float e0 = act ? __expf(r0 - m0) : 0.f;
        float e1 = act ? __expf(r1 - m1) : 0.f;
        float e2 = act ? __expf(r2 - m2) : 0.f;
        float e3 = act ? __expf(r3 - m3) : 0.f;
        float s0 = e0, s1 = e1, s2 = e2, s3 = e3;
#pragma unroll
        for (int s = 1; s < 64; s <<= 1) {
            s0 += __shfl_xor(s0, s); s1 += __shfl_xor(s1, s);
            s2 += __shfl_xor(s2, s); s3 += __shfl_xor(s3, s);
        }
        float a0 = e0 / (s0 + 1e-16f), a1 = e1 / (s1 + 1e-16f);
        float a2 = e2 / (s2 + 1e-16f), a3 = e3 / (s3 + 1e-16f);

        g[0] = a0 * a0; g[1] = a0 * a1; g[2] = a0 * a2; g[3] = a0 * a3;
        g[4] = a1 * a1; g[5] = a1 * a2; g[6] = a1 * a3;
        g[7] = a2 * a2; g[8] = a2 * a3; g[9] = a3 * a3;

        // inactive lanes: alpha = 0, col = n -> safe padding
        ashT[w][0][l] = a0; ashT[w][1][l] = a1;
        ashT[w][2][l] = a2; ashT[w][3][l] = a3;
        csh[w][l] = c;

        // ---- aggregation: branch-free 8-wide, 8 gathers in flight ----
        // (16-wide measured WORSE: VGPR 40->64, occupancy 58->40, +16 us. Keep 8.)
        const int nit = (total + 7) & ~7;
        for (int e = 0; e < nit; e += 8) {
            float4 ba = *(const float4*)&ashT[w][hsel][e];
            float4 bb = *(const float4*)&ashT[w][hsel][e + 4];
            int4 ca = *(const int4*)&csh[w][e];
            int4 cb = *(const int4*)&csh[w][e + 4];
            half4 v0 = c4[(size_t)ca.x * 64 + lane];
            half4 v1 = c4[(size_t)ca.y * 64 + lane];
            half4 v2 = c4[(size_t)ca.z * 64 + lane];
            half4 v3 = c4[(size_t)ca.w * 64 + lane];
            half4 v4 = c4[(size_t)cb.x * 64 + lane];
            half4 v5 = c4[(size_t)cb.y * 64 + lane];
            half4 v6 = c4[(size_t)cb.z * 64 + lane];
            half4 v7 = c4[(size_t)cb.w * 64 + lane];
            acc.x += ba.x * (float)v0[0] + ba.y * (float)v1[0] + ba.z * (float)v2[0] + ba.w * (float)v3[0]
                   + bb.x * (float)v4[0] + bb.y * (float)v5[0] + bb.z * (float)v6[0] + bb.w * (float)v7[0];
            acc.y += ba.x * (float)v0[1] + ba.y * (float)v1[1] + ba.z * (float)v2[1] + ba.w * (float)v3[1]
                   + bb.x * (float)v4[1] + bb.y * (float)v5[1] + bb.z * (float)v6[1] + bb.w * (float)v7[1];
            acc.z += ba.x * (float)v0[2] + ba.y * (float)v1[2] + ba.z * (float)v2[2] + ba.w * (float)v3[2]
                   + bb.x * (float)v4[2] + bb.y * (float)v5[2] + bb.z * (float)v6[2] + bb.w * (float)v7[2];
            acc.w += ba.x * (float)v0[3] + ba.y * (float)v1[3] + ba.z * (float)v2[3] + ba.w * (float)v3[3]
                   + bb.x * (float)v4[3] + bb.y * (float)v5[3] + bb.z * (float)v6[3] + bb.w * (float)v7[3];
        }
    } else {
        // ---- generic chunked path (degree >= 64; essentially never) ----
        const int nch = (total + 63) >> 6;
        float m0 = -1e30f, m1 = -1e30f, m2 = -1e30f, m3 = -1e30f;
        for (int ch = 0; ch < nch; ch++) {
            int l = ch * 64 + lane;
            if (l < total) {
                int c = (l < cnt) ? sorted[base + l] : n;
                float4 sd = *(const float4*)&sdst[c * 4];
                float r0 = ss.x + sd.x; r0 = r0 > 0.f ? r0 : NEG * r0;
                float r1 = ss.y + sd.y; r1 = r1 > 0.f ? r1 : NEG * r1;
                float r2 = ss.z + sd.z; r2 = r2 > 0.f ? r2 : NEG * r2;
                float r3 = ss.w + sd.w; r3 = r3 > 0.f ? r3 : NEG * r3;
                m0 = fmaxf(m0, r0); m1 = fmaxf(m1, r1);
                m2 = fmaxf(m2, r2); m3 = fmaxf(m3, r3);
            }
        }
#pragma unroll
        for (int s = 1; s < 64; s <<= 1) {
            m0 = fmaxf(m0, __shfl_xor(m0, s));
            m1 = fmaxf(m1, __shfl_xor(m1, s));
            m2 = fmaxf(m2, __shfl_xor(m2, s));
            m3 = fmaxf(m3, __shfl_xor(m3, s));
        }
        float s0 = 0.f, s1 = 0.f, s2 = 0.f, s3 = 0.f;
        for (int ch = 0; ch < nch; ch++) {
            int l = ch * 64 + lane;
            if (l < total) {
                int c = (l < cnt) ? sorted[base + l] : n;
                float4 sd = *(const float4*)&sdst[c * 4];
                float r0 = ss.x + sd.x; r0 = r0 > 0.f ? r0 : NEG * r0;
                float r1 = ss.y + sd.y; r1 = r1 > 0.f ? r1 : NEG * r1;
                float r2 = ss.z + sd.z; r2 = r2 > 0.f ? r2 : NEG * r2;
                float r3 = ss.w + sd.w; r3 = r3 > 0.f ? r3 : NEG * r3;
                s0 += __expf(r0 - m0); s1 += __expf(r1 - m1);
                s2 += __expf(r2 - m2); s3 += __expf(r3 - m3);
            }
        }
#pragma unroll
        for (int s = 1; s < 64; s <<= 1) {
            s0 += __shfl_xor(s0, s); s1 += __shfl_xor(s1, s);
            s2 += __shfl_xor(s2, s); s3 += __shfl_xor(s3, s);
        }
        const float i0 = 1.f / (s0 + 1e-16f), i1 = 1.f / (s1 + 1e-16f);
        const float i2 = 1.f / (s2 + 1e-16f), i3 = 1.f / (s3 + 1e-16f);

        for (int ch = 0; ch < nch; ch++) {
            int l = ch * 64 + lane;
            int c = n;
            float a0 = 0.f, a1 = 0.f, a2 = 0.f, a3 = 0.f;
            if (l < total) {
                c = (l < cnt) ? sorted[base + l] : n;
                float4 sd = *(const float4*)&sdst[c * 4];
                float r0 = ss.x + sd.x; r0 = r0 > 0.f ? r0 : NEG * r0;
                float r1 = ss.y + sd.y; r1 = r1 > 0.f ? r1 : NEG * r1;
                float r2 = ss.z + sd.z; r2 = r2 > 0.f ? r2 : NEG * r2;
                float r3 = ss.w + sd.w; r3 = r3 > 0.f ? r3 : NEG * r3;
                a0 = __expf(r0 - m0) * i0; a1 = __expf(r1 - m1) * i1;
                a2 = __expf(r2 - m2) * i2; a3 = __expf(r3 - m3) * i3;
            }
            g[0] += a0 * a0; g[1] += a0 * a1; g[2] += a0 * a2; g[3] += a0 * a3;
            g[4] += a1 * a1; g[5] += a1 * a2; g[6] += a1 * a3;
            g[7] += a2 * a2; g[8] += a2 * a3; g[9] += a3 * a3;

            int cc = min(64, total - ch * 64);
            for (int e = 0; e < cc; e++) {
                float b0 = __shfl(a0, e), b1 = __shfl(a1, e);
                float b2 = __shfl(a2, e), b3 = __shfl(a3, e);
                int ce = __shfl(c, e);
                float mya = hsel == 0 ? b0 : hsel == 1 ? b1 : hsel == 2 ? b2 : b3;
                half4 cv = c4[(size_t)ce * 64 + lane];
                acc.x += mya * (float)cv[0]; acc.y += mya * (float)cv[1];
                acc.z += mya * (float)cv[2]; acc.w += mya * (float)cv[3];
            }
        }
    }

    float4 bv = ((const float4*)bias)[lane];
    acc.x += bv.x; acc.y += bv.y; acc.z += bv.z; acc.w += bv.w;
    ((float4*)out)[(size_t)n * 64 + lane] = acc;

    // gram: wave reduce -> LDS -> per-block partial STORE (no global atomics)
#pragma unroll
    for (int s = 1; s < 64; s <<= 1) {
#pragma unroll
        for (int k = 0; k < 10; k++) g[k] += __shfl_xor(g[k], s);
    }
    if (lane == 0) {
#pragma unroll
        for (int k = 0; k < 10; k++) atomicAdd(&gsh[k], g[k]);
    }
    __syncthreads();
    if (threadIdx.x < 10) gpart[(size_t)blockIdx.x * 10 + threadIdx.x] = gsh[threadIdx.x];
}

// ---------------- gram reduction + diversity loss ----------------
__global__ __launch_bounds__(1024) void k_final(const float* __restrict__ gpart,
                                                float* __restrict__ out_div) {
    __shared__ float s[1024];
    const int t = threadIdx.x;
    const int k = t & 15, grp = t >> 4;   // 64 groups x 16 slots
    float v = 0.f;
    if (k < 10) {
        for (int b = grp; b < NBLK; b += 64) v += gpart[(size_t)b * 10 + k];
    }
    s[t] = v;
    __syncthreads();
    for (int off = 512; off >= 16; off >>= 1) {
        if (t < off) s[t] += s[t + off];
        __syncthreads();
    }
    if (t == 0) {
        float g00 = s[0], g01 = s[1], g02 = s[2], g03 = s[3];
        float g11 = s[4], g12 = s[5], g13 = s[6];
        float g22 = s[7], g23 = s[8], g33 = s[9];
        float n0 = fmaxf(sqrtf(g00), 1e-8f), n1 = fmaxf(sqrtf(g11), 1e-8f);
        float n2 = fmaxf(sqrtf(g22), 1e-8f), n3 = fmaxf(sqrtf(g33), 1e-8f);
        float sum = g01 / (n0 * n1) + g02 / (n0 * n2) + g03 / (n0 * n3) +
                    g12 / (n1 * n2) + g13 / (n1 * n3) + g23 / (n2 * n3);
        sum *= 2.0f;
        out_div[0] = sum / 16.0f * 0.1f;
    }
}

extern "C" void kernel_launch(void* const* d_in, const int* in_sizes, int n_in,
                              void* d_out, int out_size, void* d_ws, size_t ws_size,
                              hipStream_t stream) {
    const float* x    = (const float*)d_in[0];
    const int*   ei   = (const int*)d_in[1];
    const int*   row  = ei;
    const int*   col  = ei + NE;
    const float* w    = (const float*)d_in[2];
    const float* att  = (const float*)d_in[3];
    const float* patt = (const float*)d_in[4];
    const float* bias = (const float*)d_in[5];
    float* out = (float*)d_out;

    char* p = (char*)d_ws;
    _Float16* content = (_Float16*)p; p += (size_t)NN * 256 * 2;
    _Float16* wfrag   = (_Float16*)p; p += (size_t)256 * 256 * 2;
    float* ssrc    = (float*)p; p += (size_t)NN * 4 * 4;
    float* sdst    = (float*)p; p += (size_t)NN * 4 * 4;
    float* gpart   = (float*)p; p += (size_t)NBLK * 10 * 4;
    int* counts    = (int*)p;   p += (size_t)NN * 4;
    int* offs      = (int*)p;   p += (size_t)NN * 4;
    int* gcur      = (int*)p;   p += 64;
    int* slot      = (int*)p;   p += (size_t)NE * 4;
    int* sorted    = (int*)p;   p += (size_t)NE * 4;

    k_prep<<<256, 256, 0, stream>>>(w, wfrag, counts, gcur);

    k_count<<<(NE + 255) / 256, 256, 0, stream>>>(row, counts, slot);

    k_gemm<<<(NN + 63) / 64, 256, 0, stream>>>(x, wfrag, att, patt, content, ssrc, sdst);

    int nb1 = (NN + SB - 1) / SB;
    k_offs<<<nb1, SB, 0, stream>>>(counts, offs, gcur);
    k_place<<<(NE + 255) / 256, 256, 0, stream>>>(row, col, offs, slot, sorted);

    k_node<<<NBLK, 256, 0, stream>>>(content, ssrc, sdst, counts, offs, sorted,
                                     bias, out, gpart);
    k_final<<<1, 1024, 0, stream>>>(gpart, out + (size_t)NN * 256);
}